// Round 4
// baseline (909.032 us; speedup 1.0000x reference)
//
#include <hip/hip_runtime.h>
#include <stdint.h>

typedef int   v4i __attribute__((ext_vector_type(4)));
typedef float v4f __attribute__((ext_vector_type(4)));

// LDS map:
//   [0, 2*13824)  act slots: hi at l*2304 + b*144 + k, lo at +6912
//   BIAS_OFF      fp32 bias [l][type R,Z,NX,NH][h]  (6144 B)
//   FC_OFF        fc i8 A-frags, 2 blocks of 1KB
#define SLOT_SZ  13824
#define LO_OFF   6912
#define BIAS_OFF (2*SLOT_SZ)            // 27648
#define FC_OFF   (BIAS_OFF + 6144)      // 33792
#define SMEM_SZ  (FC_OFF + 2048)        // 35840

#define QW   1436.84056f      // 127/s, s = 1/sqrt(128)
#define C1f  4.38394754e-5f   // s*8/127^2  (hi-accum scale)
#define C2f  3.45193507e-7f   // C1/127     (lo-accum scale)

__device__ __forceinline__ float sigm(float x) {
  return __builtin_amdgcn_rcpf(1.f + __expf(-x));
}
__device__ __forceinline__ float tanh_(float x) {
  return 1.f - 2.f * __builtin_amdgcn_rcpf(1.f + __expf(2.f * x));
}

// i8 weight image (unchanged): blk = l*12 + o*2 + kh; o: 0 Rx,1 Rh,2 Zx,3 Zh,4 Nx,5 Nh.
// lane(g=lane&15, q=lane>>4) holds W[row g][k = kh*64 + q*16 + j], j=0..15.
__global__ void prep_weights(const float* __restrict__ Wih,
                             const float* __restrict__ Whh,
                             int8_t* __restrict__ img) {
  int bid = blockIdx.x, lane = threadIdx.x;          // 288 blocks x 64
  int w = bid / 36, blk = bid % 36;
  int l = blk / 12, rem = blk % 12, o = rem >> 1, kh = rem & 1;
  const float* M = (o & 1) ? Whh : Wih;
  int row = (o >> 1) * 128 + w * 16 + (lane & 15);
  int k0 = kh * 64 + (lane >> 4) * 16;
  const float* src = M + l * 49152 + row * 128 + k0;
  int words[4];
  #pragma unroll
  for (int j4 = 0; j4 < 4; ++j4) {
    unsigned wd = 0;
    #pragma unroll
    for (int j = 0; j < 4; ++j) {
      int q = (int)rintf(src[j4 * 4 + j] * QW);
      wd |= ((unsigned)(q & 255)) << (8 * j);
    }
    words[j4] = (int)wd;
  }
  *(v4i*)(img + (((long)bid) * 64 + lane) * 16) = *(const v4i*)words;
}

#define MFMA8(kh, Ah, Al, base)                                                \
  aRh = __builtin_amdgcn_mfma_i32_16x16x64_i8(wr[(base) + 0 + (kh)], Ah, aRh, 0, 0, 0); \
  aRl = __builtin_amdgcn_mfma_i32_16x16x64_i8(wr[(base) + 0 + (kh)], Al, aRl, 0, 0, 0); \
  aZh = __builtin_amdgcn_mfma_i32_16x16x64_i8(wr[(base) + 4 + (kh)], Ah, aZh, 0, 0, 0); \
  aZl = __builtin_amdgcn_mfma_i32_16x16x64_i8(wr[(base) + 4 + (kh)], Al, aZl, 0, 0, 0);

#define MFMAX(kh, Ah, Al, base)                                                \
  MFMA8(kh, Ah, Al, base)                                                      \
  aXh = __builtin_amdgcn_mfma_i32_16x16x64_i8(wr[(base) + 8 + (kh)], Ah, aXh, 0, 0, 0); \
  aXl = __builtin_amdgcn_mfma_i32_16x16x64_i8(wr[(base) + 8 + (kh)], Al, aXl, 0, 0, 0);

#define MFMAH(kh, Ah, Al, base)                                                \
  MFMA8(kh, Ah, Al, (base) + 2)                                                \
  aHh = __builtin_amdgcn_mfma_i32_16x16x64_i8(wr[(base) + 10 + (kh)], Ah, aHh, 0, 0, 0); \
  aHl = __builtin_amdgcn_mfma_i32_16x16x64_i8(wr[(base) + 10 + (kh)], Al, aHl, 0, 0, 0);

__global__ __launch_bounds__(512, 2)
void gru_main(const float* __restrict__ hiddens, const float* __restrict__ bih,
              const float* __restrict__ bhh, const float* __restrict__ fcw,
              const float* __restrict__ fcb, const int8_t* __restrict__ img,
              float* __restrict__ out) {
  extern __shared__ char smem[];
  const int tid = threadIdx.x, wg = blockIdx.x;
  const int lane = tid & 63, w = tid >> 6, col = lane & 15, q = lane >> 4;

  // ---- ALL 36 weight frags in registers (144 regs) ----
  v4i wr[36];
  #pragma unroll
  for (int i = 0; i < 36; ++i)
    wr[i] = *(const v4i*)(img + (((long)(w * 36 + i)) * 64 + lane) * 16);

  // ---- fc i8 A-frags in LDS ----
  if (tid < 128) {
    int kh = tid >> 6, ln = tid & 63, c2 = ln & 15, q2 = ln >> 4;
    int words[4] = {0, 0, 0, 0};
    if (c2 < 2) {
      const float* src = fcw + c2 * 128 + kh * 64 + q2 * 16;
      #pragma unroll
      for (int j4 = 0; j4 < 4; ++j4) {
        unsigned wd = 0;
        #pragma unroll
        for (int j = 0; j < 4; ++j) {
          int qv = (int)rintf(src[j4 * 4 + j] * QW);
          wd |= ((unsigned)(qv & 255)) << (8 * j);
        }
        words[j4] = (int)wd;
      }
    }
    *(v4i*)(smem + FC_OFF + kh * 1024 + ln * 16) = *(const v4i*)words;
  }
  // ---- bias table in LDS: [l][type][h] fp32 ----
  for (int i = tid; i < 1536; i += 512) {
    int l = i >> 9, type = (i >> 7) & 3, h = i & 127;
    float bv;
    if      (type == 0) bv = bih[l * 384 + h]       + bhh[l * 384 + h];
    else if (type == 1) bv = bih[l * 384 + 128 + h] + bhh[l * 384 + 128 + h];
    else if (type == 2) bv = bih[l * 384 + 256 + h];
    else                bv = bhh[l * 384 + 256 + h];
    *(float*)(smem + BIAS_OFF + i * 4) = bv;
  }
  // ---- act slot0 init (hi/lo) ----
  for (int i = tid; i < 6144; i += 512) {
    int l = i >> 11, b = (i >> 7) & 15, h = i & 127;
    float v = hiddens[((long)(wg * 16 + b)) * 384 + l * 128 + h];
    float f = v * 15.875f, fhi = rintf(f);
    *(int8_t*)(smem + l * 2304 + b * 144 + h)          = (int8_t)(int)fhi;
    *(int8_t*)(smem + l * 2304 + b * 144 + h + LO_OFF) = (int8_t)(int)rintf((f - fhi) * 127.f);
  }
  // ---- h-state in regs: hst[l][r] = h[l][w*16+q*4+r][batch=col] ----
  v4f hst[3];
  #pragma unroll
  for (int l = 0; l < 3; ++l)
    #pragma unroll
    for (int r = 0; r < 4; ++r)
      hst[l][r] = hiddens[((long)(wg * 16 + col)) * 384 + l * 128 + w * 16 + q * 4 + r];

  const float fcb0 = fcb[0], fcb1 = fcb[1];
  __syncthreads();

  const char* fragb = smem + col * 144 + q * 16;   // B-frag lane base (n=col=batch)
  char* ewb = smem + col * 144 + w * 16 + q * 4;   // EW b32 write base
  const char* biasb = smem + BIAS_OFF + (w * 16 + q * 4) * 4;

#define EW_STORE(l)                                                            \
  {                                                                            \
    v4f bRv = *(const v4f*)(biasb + ((l) * 4 + 0) * 512);                      \
    v4f bZv = *(const v4f*)(biasb + ((l) * 4 + 1) * 512);                      \
    v4f bXv = *(const v4f*)(biasb + ((l) * 4 + 2) * 512);                      \
    v4f bHv = *(const v4f*)(biasb + ((l) * 4 + 3) * 512);                      \
    unsigned hiw = 0, low = 0;                                                 \
    _Pragma("unroll")                                                          \
    for (int r = 0; r < 4; ++r) {                                              \
      float gR = bRv[r] + C1f * (float)aRh[r] + C2f * (float)aRl[r];           \
      float gZ = bZv[r] + C1f * (float)aZh[r] + C2f * (float)aZl[r];           \
      float gX = bXv[r] + C1f * (float)aXh[r] + C2f * (float)aXl[r];           \
      float gH = bHv[r] + C1f * (float)aHh[r] + C2f * (float)aHl[r];           \
      float rg = sigm(gR), zg = sigm(gZ);                                      \
      float ng = tanh_(gX + rg * gH);                                          \
      float hn = ng + zg * (hst[l][r] - ng);                                   \
      hst[l][r] = hn;                                                          \
      float f = hn * 15.875f, fhi = rintf(f);                                  \
      hiw |= ((unsigned)(((int)fhi) & 255)) << (8 * r);                        \
      low |= ((unsigned)(((int)rintf((f - fhi) * 127.f)) & 255)) << (8 * r);   \
    }                                                                          \
    *(unsigned*)(ewb + sn + (l) * 2304)          = hiw;                        \
    *(unsigned*)(ewb + sn + (l) * 2304 + LO_OFF) = low;                        \
  }

  #pragma unroll 1
  for (int t = 0; t < 256; ++t) {
    const int so = (t & 1) * SLOT_SZ;
    const int sn = SLOT_SZ - so;

    // ================= W1: layer 0 (+FC for t-1 on wave 0) =================
    {
      v4i xh0[2], xl0[2], hh[2], hl[2];
      #pragma unroll
      for (int kh = 0; kh < 2; ++kh) {
        xh0[kh] = *(const v4i*)(fragb + so + 2 * 2304 + kh * 64);
        xl0[kh] = *(const v4i*)(fragb + so + 2 * 2304 + kh * 64 + LO_OFF);
        hh[kh]  = *(const v4i*)(fragb + so + kh * 64);
        hl[kh]  = *(const v4i*)(fragb + so + kh * 64 + LO_OFF);
      }
      v4i aRh = {0,0,0,0}, aRl = {0,0,0,0}, aZh = {0,0,0,0}, aZl = {0,0,0,0};
      v4i aXh = {0,0,0,0}, aXl = {0,0,0,0}, aHh = {0,0,0,0}, aHl = {0,0,0,0};
      #pragma unroll
      for (int kh = 0; kh < 2; ++kh) { MFMAH(kh, hh[kh], hl[kh], 0) }
      if (t > 0) {
        #pragma unroll
        for (int kh = 0; kh < 2; ++kh) { MFMAX(kh, xh0[kh], xl0[kh], 0) }
        // FC for step t-1 reuses xh0/xl0 (= layer-2 acts of t-1)
        if (w == 0) {
          v4i dh = {0,0,0,0}, dl = {0,0,0,0};
          #pragma unroll
          for (int kh = 0; kh < 2; ++kh) {
            v4i fw = *(const v4i*)(smem + FC_OFF + kh * 1024 + lane * 16);
            dh = __builtin_amdgcn_mfma_i32_16x16x64_i8(fw, xh0[kh], dh, 0, 0, 0);
            dl = __builtin_amdgcn_mfma_i32_16x16x64_i8(fw, xl0[kh], dl, 0, 0, 0);
          }
          if (q == 0) {
            float2 o2;
            o2.x = fcb0 + C1f * (float)dh[0] + C2f * (float)dl[0];
            o2.y = fcb1 + C1f * (float)dh[1] + C2f * (float)dl[1];
            *(float2*)(out + (((long)(wg * 16 + col)) * 256 + (t - 1)) * 2) = o2;
          }
        }
      }
      EW_STORE(0)
    }
    __syncthreads();

    // ================= W2: layer 1 =================
    {
      v4i xh[2], xl[2], hh[2], hl[2];
      #pragma unroll
      for (int kh = 0; kh < 2; ++kh) {
        xh[kh] = *(const v4i*)(fragb + sn + kh * 64);              // l0 new
        xl[kh] = *(const v4i*)(fragb + sn + kh * 64 + LO_OFF);
        hh[kh] = *(const v4i*)(fragb + so + 1 * 2304 + kh * 64);   // l1 old
        hl[kh] = *(const v4i*)(fragb + so + 1 * 2304 + kh * 64 + LO_OFF);
      }
      v4i aRh = {0,0,0,0}, aRl = {0,0,0,0}, aZh = {0,0,0,0}, aZl = {0,0,0,0};
      v4i aXh = {0,0,0,0}, aXl = {0,0,0,0}, aHh = {0,0,0,0}, aHl = {0,0,0,0};
      #pragma unroll
      for (int kh = 0; kh < 2; ++kh) { MFMAH(kh, hh[kh], hl[kh], 12) MFMAX(kh, xh[kh], xl[kh], 12) }
      EW_STORE(1)
    }
    __syncthreads();

    // ================= W3: layer 2 =================
    {
      v4i xh[2], xl[2], hh[2], hl[2];
      #pragma unroll
      for (int kh = 0; kh < 2; ++kh) {
        xh[kh] = *(const v4i*)(fragb + sn + 1 * 2304 + kh * 64);   // l1 new
        xl[kh] = *(const v4i*)(fragb + sn + 1 * 2304 + kh * 64 + LO_OFF);
        hh[kh] = *(const v4i*)(fragb + so + 2 * 2304 + kh * 64);   // l2 old
        hl[kh] = *(const v4i*)(fragb + so + 2 * 2304 + kh * 64 + LO_OFF);
      }
      v4i aRh = {0,0,0,0}, aRl = {0,0,0,0}, aZh = {0,0,0,0}, aZl = {0,0,0,0};
      v4i aXh = {0,0,0,0}, aXl = {0,0,0,0}, aHh = {0,0,0,0}, aHl = {0,0,0,0};
      #pragma unroll
      for (int kh = 0; kh < 2; ++kh) { MFMAH(kh, hh[kh], hl[kh], 24) MFMAX(kh, xh[kh], xl[kh], 24) }
      EW_STORE(2)
    }
    __syncthreads();
  }

  // ---- final FC for t=255: l2 acts live in slot 0 (t=255 wrote sn=0) ----
  if (w == 0) {
    v4i dh = {0,0,0,0}, dl = {0,0,0,0};
    #pragma unroll
    for (int kh = 0; kh < 2; ++kh) {
      v4i xh = *(const v4i*)(fragb + 2 * 2304 + kh * 64);
      v4i xl = *(const v4i*)(fragb + 2 * 2304 + kh * 64 + LO_OFF);
      v4i fw = *(const v4i*)(smem + FC_OFF + kh * 1024 + lane * 16);
      dh = __builtin_amdgcn_mfma_i32_16x16x64_i8(fw, xh, dh, 0, 0, 0);
      dl = __builtin_amdgcn_mfma_i32_16x16x64_i8(fw, xl, dl, 0, 0, 0);
    }
    if (q == 0) {
      float2 o2;
      o2.x = fcb0 + C1f * (float)dh[0] + C2f * (float)dl[0];
      o2.y = fcb1 + C1f * (float)dh[1] + C2f * (float)dl[1];
      *(float2*)(out + (((long)(wg * 16 + col)) * 256 + 255) * 2) = o2;
    }
  }
}

extern "C" void kernel_launch(void* const* d_in, const int* in_sizes, int n_in,
                              void* d_out, int out_size, void* d_ws, size_t ws_size,
                              hipStream_t stream) {
  (void)in_sizes; (void)n_in; (void)out_size; (void)ws_size;
  const float* hiddens = (const float*)d_in[0];
  const float* Wih     = (const float*)d_in[1];
  const float* Whh     = (const float*)d_in[2];
  const float* bih     = (const float*)d_in[3];
  const float* bhh     = (const float*)d_in[4];
  const float* fcw     = (const float*)d_in[5];
  const float* fcb     = (const float*)d_in[6];
  int8_t* img = (int8_t*)d_ws;   // 288 KB weight image
  float* out = (float*)d_out;

  prep_weights<<<288, 64, 0, stream>>>(Wih, Whh, img);
  gru_main<<<64, 512, SMEM_SZ, stream>>>(hiddens, bih, bhh, fcw, fcb, img, out);
}